// Round 7
// baseline (160.663 us; speedup 1.0000x reference)
//
#include <hip/hip_runtime.h>
#include <math.h>

#define BB 256      // batch
#define IC 1152     // in caps
#define OC 10       // out caps
#define OD 16       // out dim
#define ID 8        // in dim
#define ODOC 160

#define NCHUNK 144      // i-chunks of 8 (uhat)
#define NBG 8           // b residue groups (32 b each)
#define UK_THREADS 320  // 8 il x 40 (o,dq)

// s0 kernel: grid = 8 i-chunks (144 i, XCD-pinned) x 64 b-quads (4 b)
#define S0_ICN 8
#define S0_SEG (IC / S0_ICN)    // 144
#define S0_BQ 64
#define S0_NB 4                 // b per block
#define S0_THREADS 320          // 4 b x 80 od-pairs
#define S0_UPAD 1160            // 144*8=1152 +8 pad floats (bank shift)

#define R_THREADS 1024  // 64 il x 16 slot
#define R_IL 64
#define R_STEPS (IC/R_IL)   // 18

typedef unsigned int   u32;
typedef unsigned short u16;

__device__ __forceinline__ float grp16_sum(float x) {
#pragma unroll
    for (int m = 8; m >= 1; m >>= 1) x += __shfl_xor(x, m, 16);
    return x;
}
// squash over the 16-lane d-group
__device__ __forceinline__ float squash_val(float s) {
    float sq = grp16_sum(s * s);
    return s * (sq / ((1.f + sq) * (sqrtf(sq) + 1e-8f)));
}

__device__ __forceinline__ u32 bf16_rne(float f) {
    u32 x = __float_as_uint(f);
    return (x + 0x7FFFu + ((x >> 16) & 1u)) >> 16;
}
__device__ __forceinline__ u32 pack_bf16x2(float lo, float hi) {
    return bf16_rne(lo) | (bf16_rne(hi) << 16);
}
__device__ __forceinline__ float bf_lo(u32 v) { return __uint_as_float(v << 16); }
__device__ __forceinline__ float bf_hi(u32 v) { return __uint_as_float(v & 0xFFFF0000u); }

// Kernel 1 (round-3 verbatim — proven ~31 us at the write roofline). PURE:
// no s0, no atomics, no extra LDS — the dense lockstep write window is
// fragile to any per-iter latency variance (rounds 4/5 evidence).
__global__ __launch_bounds__(UK_THREADS) void uhat_kernel(const float* __restrict__ u,
                                                          const float* __restrict__ W,
                                                          u16* __restrict__ uhat) {
    __shared__ float us[32][8][ID];   // 8 KB

    const int t = threadIdx.x;
    const int chunk = blockIdx.x % NCHUNK;
    const int bg    = blockIdx.x / NCHUNK;    // 0..7
    const int i0 = chunk * 8;

    for (int idx = t; idx < 32 * 8 * ID; idx += UK_THREADS) {
        int bb = idx >> 6, r = idx & 63, il = r >> 3, k = r & 7;
        us[bb][il][k] = u[((size_t)(bb * NBG + bg) * IC + (i0 + il)) * ID + k];
    }
    __syncthreads();

    const int il = t / 40;
    const int r  = t % 40;
    const int o  = r >> 2;
    const int dq = r & 3;
    const int i  = i0 + il;

    float w[4][ID];
    const float* wp = W + (((size_t)i * OC + o) * OD + dq * 4) * ID;
#pragma unroll
    for (int j = 0; j < 4; j++)
#pragma unroll
        for (int k = 0; k < ID; k++) w[j][k] = wp[j * ID + k];

    for (int bb = 0; bb < 32; ++bb) {
        const int b = bb * NBG + bg;
        float a0 = 0.f, a1 = 0.f, a2 = 0.f, a3 = 0.f;
#pragma unroll
        for (int k = 0; k < ID; k++) {
            float uu = us[bb][il][k];
            a0 += w[0][k] * uu;
            a1 += w[1][k] * uu;
            a2 += w[2][k] * uu;
            a3 += w[3][k] * uu;
        }
        uint2 pk = make_uint2(pack_bf16x2(a0, a1), pack_bf16x2(a2, a3));
        *(uint2*)(uhat + ((size_t)b * IC + i) * ODOC + o * OD + dq * 4) = pk;
    }
}

// s0 kernel: s0[b,od] = sum_{i,k} W[i,od,k] * u[b,i,k]  (f32, direct from
// inputs — kills routing's pass-0 94 MB slab re-read). Thread = (b_l 0..3,
// odp 0..79): 2 od rows = 64 B contiguous W load shared by 4 b-lanes
// (same-wave broadcast). i-chunk = blockIdx&7 -> XCD-pinned so the 737 KB
// W-chunk stays L2-hot across its 64 b-blocks. u staged in padded LDS
// ([4][1160]: +8-float shift per b -> conflict-free ds_read_b128).
__global__ __launch_bounds__(S0_THREADS) void s0_kernel(const float* __restrict__ u,
                                                        const float* __restrict__ W,
                                                        float* __restrict__ s0g) {
    __shared__ float ush[S0_NB][S0_UPAD];   // 18.6 KB

    const int t  = threadIdx.x;
    const int ic = blockIdx.x & 7;          // XCD-pinned chunk
    const int bq = blockIdx.x >> 3;         // 0..63
    const int i0 = ic * S0_SEG;
    const int b0 = bq * S0_NB;

    for (int idx = t; idx < S0_NB * S0_SEG * ID; idx += S0_THREADS) {
        int bl = idx / (S0_SEG * ID), r = idx % (S0_SEG * ID);
        ush[bl][r] = u[((size_t)(b0 + bl) * IC + i0) * ID + r];
    }
    __syncthreads();

    const int bl  = t / 80;      // 0..3
    const int odp = t % 80;      // 0..79 (od pair)

    float acc0 = 0.f, acc1 = 0.f;
    const float* wbase = W + ((size_t)i0 * ODOC + odp * 2) * ID;

#pragma unroll 4
    for (int i = 0; i < S0_SEG; ++i) {
        float4 ua = *(const float4*)&ush[bl][i * ID];
        float4 ub = *(const float4*)&ush[bl][i * ID + 4];
        const float4* wp = (const float4*)(wbase + (size_t)i * ODOC * ID);
        float4 w0 = wp[0], w1 = wp[1], w2 = wp[2], w3 = wp[3];
        acc0 += w0.x * ua.x + w0.y * ua.y + w0.z * ua.z + w0.w * ua.w
              + w1.x * ub.x + w1.y * ub.y + w1.z * ub.z + w1.w * ub.w;
        acc1 += w2.x * ua.x + w2.y * ua.y + w2.z * ua.z + w2.w * ua.w
              + w3.x * ub.x + w3.y * ub.y + w3.z * ub.z + w3.w * ub.w;
    }

    atomicAdd(&s0g[(size_t)(b0 + bl) * ODOC + odp * 2],     acc0);
    atomicAdd(&s0g[(size_t)(b0 + bl) * ODOC + odp * 2 + 1], acc1);
}

// Routing: one b per block, 1024 threads = 64 i-lanes x 16 slots (slot = o
// for slot<10). v0 from s0g (pass-0 slab read ELIMINATED). Two fused passes;
// logits in registers (Lreg[18], static index via full unroll); softmax
// without max-subtraction (|logit| <~ 12, shift-invariant). No LDS/barriers
// in the step loops.
__global__ __launch_bounds__(R_THREADS, 4) void routing_kernel(const u16* __restrict__ uhat,
                                                               const float* __restrict__ s0g,
                                                               float* __restrict__ out) {
    __shared__ float v_sh[ODOC];
    __shared__ float red[R_IL * ODOC];   // 40 KB

    const int t = threadIdx.x;
    const int b = blockIdx.x;
    const int il   = t >> 4;           // 0..63
    const int slot = t & 15;
    const bool act = slot < OC;

    if (t < ODOC) v_sh[t] = squash_val(s0g[(size_t)b * ODOC + t] * 0.1f);
    __syncthreads();

    const u16* ub = uhat + (size_t)b * IC * ODOC;

    float Lreg[R_STEPS];
#pragma unroll
    for (int j = 0; j < R_STEPS; ++j) Lreg[j] = 0.f;

#pragma unroll 1
    for (int pass = 1; pass <= 2; ++pass) {
        float vr[OD];
#pragma unroll
        for (int q = 0; q < 4; q++) {
            float4 vq = *(const float4*)&v_sh[slot * OD + q * 4];
            vr[q * 4 + 0] = vq.x; vr[q * 4 + 1] = vq.y;
            vr[q * 4 + 2] = vq.z; vr[q * 4 + 3] = vq.w;
        }
        float sp[OD];
#pragma unroll
        for (int d = 0; d < OD; ++d) sp[d] = 0.f;

#pragma unroll
        for (int step = 0; step < R_STEPS; ++step) {
            const int i = step * R_IL + il;
            float uh[OD];
            float e = 0.f;
            if (act) {
                const uint4* p = (const uint4*)(ub + (size_t)i * ODOC + slot * OD);
                uint4 A = p[0], B = p[1];
                uh[0]  = bf_lo(A.x); uh[1]  = bf_hi(A.x);
                uh[2]  = bf_lo(A.y); uh[3]  = bf_hi(A.y);
                uh[4]  = bf_lo(A.z); uh[5]  = bf_hi(A.z);
                uh[6]  = bf_lo(A.w); uh[7]  = bf_hi(A.w);
                uh[8]  = bf_lo(B.x); uh[9]  = bf_hi(B.x);
                uh[10] = bf_lo(B.y); uh[11] = bf_hi(B.y);
                uh[12] = bf_lo(B.z); uh[13] = bf_hi(B.z);
                uh[14] = bf_lo(B.w); uh[15] = bf_hi(B.w);
                float a = 0.f;
#pragma unroll
                for (int d = 0; d < OD; d++) a += uh[d] * vr[d];
                Lreg[step] += a;
                e = __expf(Lreg[step]);   // no max-sub: |logit| <~ 12, safe
            }
            float S = grp16_sum(e);
            float c = e / S;
            if (act) {
#pragma unroll
                for (int d = 0; d < OD; d++) sp[d] += c * uh[d];
            }
        }

        if (act) {
#pragma unroll
            for (int q = 0; q < 4; q++)
                *(float4*)&red[il * ODOC + slot * OD + q * 4] =
                    make_float4(sp[q * 4], sp[q * 4 + 1], sp[q * 4 + 2], sp[q * 4 + 3]);
        }
        __syncthreads();
        float sn = 0.f;
        if (t < ODOC) {
#pragma unroll 8
            for (int j = 0; j < R_IL; j++) sn += red[j * ODOC + t];
        }
        float vn = squash_val(sn);
        __syncthreads();
        if (pass == 1) {
            if (t < ODOC) v_sh[t] = vn;
            __syncthreads();
        } else {
            if (t < ODOC) out[(size_t)b * ODOC + t] = vn;
        }
    }
}

extern "C" void kernel_launch(void* const* d_in, const int* in_sizes, int n_in,
                              void* d_out, int out_size, void* d_ws, size_t ws_size,
                              hipStream_t stream) {
    const float* u = (const float*)d_in[0];
    const float* W = (const float*)d_in[1];
    float* out = (float*)d_out;

    const size_t uhat_bytes = (size_t)BB * IC * ODOC * sizeof(u16);   // 94,371,840
    u16*   uhat = (u16*)d_ws;
    float* s0g  = (float*)((char*)d_ws + uhat_bytes);

    hipMemsetAsync(s0g, 0, (size_t)BB * ODOC * sizeof(float), stream);
    hipLaunchKernelGGL(s0_kernel, dim3(S0_ICN * S0_BQ), dim3(S0_THREADS), 0, stream,
                       u, W, s0g);
    hipLaunchKernelGGL(uhat_kernel, dim3(NCHUNK * NBG), dim3(UK_THREADS), 0, stream,
                       u, W, uhat);
    hipLaunchKernelGGL(routing_kernel, dim3(BB), dim3(R_THREADS), 0, stream,
                       uhat, s0g, out);
}

// Round 8
// 159.980 us; speedup vs baseline: 1.0043x; 1.0043x over previous
//
#include <hip/hip_runtime.h>
#include <math.h>

#define BB 256      // batch
#define IC 1152     // in caps
#define OC 10       // out caps
#define OD 16       // out dim
#define ID 8        // in dim
#define ODOC 160

#define NCHUNK 144      // i-chunks of 8 (uhat)
#define NBG 8           // b residue groups (32 b each)
#define UK_THREADS 320  // 8 il x 40 (o,dq)

#define R_THREADS 1024  // 64 il x 16 slot
#define R_IL 64
#define R_STEPS (IC/R_IL)   // 18

typedef unsigned int   u32;
typedef unsigned short u16;

__device__ __forceinline__ float grp16_sum(float x) {
#pragma unroll
    for (int m = 8; m >= 1; m >>= 1) x += __shfl_xor(x, m, 16);
    return x;
}
// squash over the 16-lane d-group
__device__ __forceinline__ float squash_val(float s) {
    float sq = grp16_sum(s * s);
    return s * (sq / ((1.f + sq) * (sqrtf(sq) + 1e-8f)));
}

__device__ __forceinline__ u32 bf16_rne(float f) {
    u32 x = __float_as_uint(f);
    return (x + 0x7FFFu + ((x >> 16) & 1u)) >> 16;
}
__device__ __forceinline__ u32 pack_bf16x2(float lo, float hi) {
    return bf16_rne(lo) | (bf16_rne(hi) << 16);
}
__device__ __forceinline__ float bf_lo(u32 v) { return __uint_as_float(v << 16); }
__device__ __forceinline__ float bf_hi(u32 v) { return __uint_as_float(v & 0xFFFF0000u); }

// Kernel 1: round-3 store loop BYTE-FOR-BYTE (proven ~31 us write roofline),
// then a post-loop s0 phase-reduce: recompute accs (W regs + us LDS still
// live; 1024 extra FMAs) in 8 phases of 4 b's. Phase = non-atomic LDS float4
// stores -> barrier -> 8-way il-reduce -> 2 global atomics/thread. The bb
// store loop itself has ZERO added instructions (r4/r5 lesson).
__global__ __launch_bounds__(UK_THREADS) void uhat_kernel(const float* __restrict__ u,
                                                          const float* __restrict__ W,
                                                          u16* __restrict__ uhat,
                                                          float* __restrict__ s0g) {
    __shared__ float us[32][8][ID];       // 8 KB
    __shared__ float part[8][4][ODOC];    // 20.5 KB

    const int t = threadIdx.x;
    const int chunk = blockIdx.x % NCHUNK;
    const int bg    = blockIdx.x / NCHUNK;    // 0..7
    const int i0 = chunk * 8;

    for (int idx = t; idx < 32 * 8 * ID; idx += UK_THREADS) {
        int bb = idx >> 6, r = idx & 63, il = r >> 3, k = r & 7;
        us[bb][il][k] = u[((size_t)(bb * NBG + bg) * IC + (i0 + il)) * ID + k];
    }
    __syncthreads();

    const int il = t / 40;
    const int r  = t % 40;
    const int o  = r >> 2;
    const int dq = r & 3;
    const int i  = i0 + il;

    float w[4][ID];
    const float* wp = W + (((size_t)i * OC + o) * OD + dq * 4) * ID;
#pragma unroll
    for (int j = 0; j < 4; j++)
#pragma unroll
        for (int k = 0; k < ID; k++) w[j][k] = wp[j * ID + k];

    // ---- pristine store loop (round-3 verbatim) ----
    for (int bb = 0; bb < 32; ++bb) {
        const int b = bb * NBG + bg;
        float a0 = 0.f, a1 = 0.f, a2 = 0.f, a3 = 0.f;
#pragma unroll
        for (int k = 0; k < ID; k++) {
            float uu = us[bb][il][k];
            a0 += w[0][k] * uu;
            a1 += w[1][k] * uu;
            a2 += w[2][k] * uu;
            a3 += w[3][k] * uu;
        }
        uint2 pk = make_uint2(pack_bf16x2(a0, a1), pack_bf16x2(a2, a3));
        *(uint2*)(uhat + ((size_t)b * IC + i) * ODOC + o * OD + dq * 4) = pk;
    }

    // ---- post-loop s0 phase-reduce (8 phases x 4 b) ----
#pragma unroll 1
    for (int phase = 0; phase < 8; ++phase) {
#pragma unroll
        for (int bi = 0; bi < 4; ++bi) {
            const int bb = phase * 4 + bi;
            float a0 = 0.f, a1 = 0.f, a2 = 0.f, a3 = 0.f;
#pragma unroll
            for (int k = 0; k < ID; k++) {
                float uu = us[bb][il][k];
                a0 += w[0][k] * uu;
                a1 += w[1][k] * uu;
                a2 += w[2][k] * uu;
                a3 += w[3][k] * uu;
            }
            *(float4*)&part[il][bi][r * 4] = make_float4(a0, a1, a2, a3);
        }
        __syncthreads();
        // reduce 4*160=640 outputs over 8 il's; 2 outputs per thread
#pragma unroll
        for (int q = 0; q < 2; ++q) {
            int idx = t * 2 + q;            // 0..639
            int bi = idx / ODOC, od = idx % ODOC;
            float s = 0.f;
#pragma unroll
            for (int j = 0; j < 8; j++) s += part[j][bi][od];
            atomicAdd(&s0g[(size_t)((phase * 4 + bi) * NBG + bg) * ODOC + od], s);
        }
        __syncthreads();   // part reads done before next phase overwrites
    }
}

// Routing (r7 verbatim, proven ~29 us): one b per block, 1024 threads =
// 64 i-lanes x 16 slots (slot = o for slot<10). v0 from s0g. Two fused
// passes; logits in registers (Lreg[18], static index via full unroll);
// softmax without max-subtraction (|logit| <~ 12, shift-invariant).
// No LDS/barriers in the step loops.
__global__ __launch_bounds__(R_THREADS, 4) void routing_kernel(const u16* __restrict__ uhat,
                                                               const float* __restrict__ s0g,
                                                               float* __restrict__ out) {
    __shared__ float v_sh[ODOC];
    __shared__ float red[R_IL * ODOC];   // 40 KB

    const int t = threadIdx.x;
    const int b = blockIdx.x;
    const int il   = t >> 4;           // 0..63
    const int slot = t & 15;
    const bool act = slot < OC;

    if (t < ODOC) v_sh[t] = squash_val(s0g[(size_t)b * ODOC + t] * 0.1f);
    __syncthreads();

    const u16* ub = uhat + (size_t)b * IC * ODOC;

    float Lreg[R_STEPS];
#pragma unroll
    for (int j = 0; j < R_STEPS; ++j) Lreg[j] = 0.f;

#pragma unroll 1
    for (int pass = 1; pass <= 2; ++pass) {
        float vr[OD];
#pragma unroll
        for (int q = 0; q < 4; q++) {
            float4 vq = *(const float4*)&v_sh[slot * OD + q * 4];
            vr[q * 4 + 0] = vq.x; vr[q * 4 + 1] = vq.y;
            vr[q * 4 + 2] = vq.z; vr[q * 4 + 3] = vq.w;
        }
        float sp[OD];
#pragma unroll
        for (int d = 0; d < OD; ++d) sp[d] = 0.f;

#pragma unroll
        for (int step = 0; step < R_STEPS; ++step) {
            const int i = step * R_IL + il;
            float uh[OD];
            float e = 0.f;
            if (act) {
                const uint4* p = (const uint4*)(ub + (size_t)i * ODOC + slot * OD);
                uint4 A = p[0], B = p[1];
                uh[0]  = bf_lo(A.x); uh[1]  = bf_hi(A.x);
                uh[2]  = bf_lo(A.y); uh[3]  = bf_hi(A.y);
                uh[4]  = bf_lo(A.z); uh[5]  = bf_hi(A.z);
                uh[6]  = bf_lo(A.w); uh[7]  = bf_hi(A.w);
                uh[8]  = bf_lo(B.x); uh[9]  = bf_hi(B.x);
                uh[10] = bf_lo(B.y); uh[11] = bf_hi(B.y);
                uh[12] = bf_lo(B.z); uh[13] = bf_hi(B.z);
                uh[14] = bf_lo(B.w); uh[15] = bf_hi(B.w);
                float a = 0.f;
#pragma unroll
                for (int d = 0; d < OD; d++) a += uh[d] * vr[d];
                Lreg[step] += a;
                e = __expf(Lreg[step]);   // no max-sub: |logit| <~ 12, safe
            }
            float S = grp16_sum(e);
            float c = e / S;
            if (act) {
#pragma unroll
                for (int d = 0; d < OD; d++) sp[d] += c * uh[d];
            }
        }

        if (act) {
#pragma unroll
            for (int q = 0; q < 4; q++)
                *(float4*)&red[il * ODOC + slot * OD + q * 4] =
                    make_float4(sp[q * 4], sp[q * 4 + 1], sp[q * 4 + 2], sp[q * 4 + 3]);
        }
        __syncthreads();
        float sn = 0.f;
        if (t < ODOC) {
#pragma unroll 8
            for (int j = 0; j < R_IL; j++) sn += red[j * ODOC + t];
        }
        float vn = squash_val(sn);
        __syncthreads();
        if (pass == 1) {
            if (t < ODOC) v_sh[t] = vn;
            __syncthreads();
        } else {
            if (t < ODOC) out[(size_t)b * ODOC + t] = vn;
        }
    }
}

extern "C" void kernel_launch(void* const* d_in, const int* in_sizes, int n_in,
                              void* d_out, int out_size, void* d_ws, size_t ws_size,
                              hipStream_t stream) {
    const float* u = (const float*)d_in[0];
    const float* W = (const float*)d_in[1];
    float* out = (float*)d_out;

    const size_t uhat_bytes = (size_t)BB * IC * ODOC * sizeof(u16);   // 94,371,840
    u16*   uhat = (u16*)d_ws;
    float* s0g  = (float*)((char*)d_ws + uhat_bytes);

    hipMemsetAsync(s0g, 0, (size_t)BB * ODOC * sizeof(float), stream);
    hipLaunchKernelGGL(uhat_kernel, dim3(NCHUNK * NBG), dim3(UK_THREADS), 0, stream,
                       u, W, uhat, s0g);
    hipLaunchKernelGGL(routing_kernel, dim3(BB), dim3(R_THREADS), 0, stream,
                       uhat, s0g, out);
}